// Round 4
// baseline (114.680 us; speedup 1.0000x reference)
//
#include <hip/hip_runtime.h>
#include <hip/hip_bf16.h>

#define BATCH     16384
#define INFEAT    4096
#define NCHUNK    8
#define CIN       512
#define COUT      512
#define ACT_GRID  2048
#define ROWS_PER_BLOCK (BATCH / ACT_GRID)   // 8
#define OUT_MAIN  (BATCH * 1024)            // 16777216 f32 elements

typedef short bf16x8 __attribute__((ext_vector_type(8)));
typedef float f32x4  __attribute__((ext_vector_type(4)));

static __device__ inline unsigned short f2bf_rne(float f) {
    unsigned int u = __builtin_bit_cast(unsigned int, f);
    unsigned int r = (u + 0x7fffu + ((u >> 16) & 1u)) >> 16;
    return (unsigned short)r;
}

// ---------------- Stage 1: per-block partial abs-sums (no atomics) ----------------
__global__ __launch_bounds__(256, 4)
void act_partial_kernel(const float* __restrict__ x, float* __restrict__ part) {
    int t = threadIdx.x;
    float acc[4] = {0.f, 0.f, 0.f, 0.f};
    int r0 = blockIdx.x * ROWS_PER_BLOCK;
    for (int r = 0; r < ROWS_PER_BLOCK; ++r) {
        const float4* p = reinterpret_cast<const float4*>(x + (size_t)(r0 + r) * INFEAT);
#pragma unroll
        for (int c = 0; c < 4; ++c) {
            float4 v = p[c * 256 + t];
            acc[c] += fabsf(v.x) + fabsf(v.y) + fabsf(v.z) + fabsf(v.w);
        }
    }
#pragma unroll
    for (int c = 0; c < 4; ++c) {
        float v = acc[c];
        v += __shfl_xor(v, 32);
        v += __shfl_xor(v, 16);
        v += __shfl_xor(v, 8);
        v += __shfl_xor(v, 4);
        v += __shfl_xor(v, 2);
        v += __shfl_xor(v, 1);
        acc[c] = v;
    }
    __shared__ float sred[16];
    int wave = t >> 6, lane = t & 63;
    if (lane == 0) {
#pragma unroll
        for (int c = 0; c < 4; ++c) sred[wave * 4 + c] = acc[c];
    }
    __syncthreads();
    if (t < 8) {
        // chunk k = t: slot chunk = 2c + (t>>7) -> c = k>>1, waves 2*(k&1), 2*(k&1)+1
        int c = t >> 1, hi = t & 1;
        float s = sred[(2 * hi) * 4 + c] + sred[(2 * hi + 1) * 4 + c];
        part[blockIdx.x * 8 + t] = s;
    }
}

// ---------------- Stage 2: final reduce (f64), top-2, write outputs (f32) ----------------
__global__ void finalize_topk_kernel(const float* __restrict__ part,
                                     float* __restrict__ out_act,   // 8 f32
                                     float* __restrict__ out_idx,   // 2 f32 (index values)
                                     int* __restrict__ ws_idx) {
    int t = threadIdx.x;
    __shared__ double sd[256];
    __shared__ double act[8];
    int k = t & 7, s = t >> 3;
    double a = 0.0;
    for (int i = s; i < ACT_GRID; i += 32) a += (double)part[i * 8 + k];
    sd[t] = a;
    __syncthreads();
    if (t < 8) {
        double tot = 0.0;
        for (int j = 0; j < 32; ++j) tot += sd[t + 8 * j];
        double m = tot / ((double)BATCH * (double)CIN);
        act[t] = m;
        out_act[t] = (float)m;
    }
    __syncthreads();
    if (t == 0) {
        int i0 = 0;
        for (int i = 1; i < 8; ++i) if (act[i] > act[i0]) i0 = i;
        int i1 = -1;
        for (int i = 0; i < 8; ++i) {
            if (i == i0) continue;
            if (i1 < 0 || act[i] > act[i1]) i1 = i;
        }
        out_idx[0] = (float)i0;
        out_idx[1] = (float)i1;
        ws_idx[0] = i0;
        ws_idx[1] = i1;
    }
}

// ---------------- Stage 3a: transpose+convert selected W chunks to bf16 (n-major) ----------------
__global__ void wtrans_kernel(const float* __restrict__ W, const int* __restrict__ idx,
                              unsigned short* __restrict__ WT) {
    // grid (16,16,2), block (32,8). WT[c][o][i] = bf16(W[idx[c]][i][o])
    int c = blockIdx.z;
    int id = idx[c];
    __shared__ float tile[32][33];
    int tx = threadIdx.x, ty = threadIdx.y;
    const float* Wp = W + (size_t)id * (CIN * COUT);
    int i0 = blockIdx.x * 32, o0 = blockIdx.y * 32;
#pragma unroll
    for (int r = 0; r < 4; ++r)
        tile[ty + r * 8][tx] = Wp[(size_t)(i0 + ty + r * 8) * COUT + o0 + tx];
    __syncthreads();
    unsigned short* WTp = WT + (size_t)c * (CIN * COUT);
#pragma unroll
    for (int r = 0; r < 4; ++r)
        WTp[(size_t)(o0 + ty + r * 8) * CIN + i0 + tx] = f2bf_rne(tile[tx][ty + r * 8]);
}

// ---------------- Stage 3b: GEMM (bf16 MFMA), 128x128 tile, BK=32, f32 output ----------------
#define LDA 40   // padded row stride in shorts (80 B)
__global__ __launch_bounds__(256, 2)
void gemm_topk_kernel(const float* __restrict__ x, const unsigned short* __restrict__ WT,
                      const float* __restrict__ bvec, const int* __restrict__ idxp,
                      float* __restrict__ out) {
    __shared__ __align__(16) unsigned short As[128 * LDA];
    __shared__ __align__(16) unsigned short Bs[128 * LDA];

    int c = blockIdx.z;
    int idx = idxp[c];
    int brow = blockIdx.x * 128;
    int bn   = blockIdx.y * 128;
    int t = threadIdx.x;
    int lane = t & 63, wid = t >> 6;
    int wm = wid >> 1, wn = wid & 1;
    int lrow = lane & 15, lgrp = lane >> 4;

    f32x4 acc[4][4] = {};

    const float* xbase = x + (size_t)brow * INFEAT + idx * CIN;
    const unsigned short* wtbase = WT + (size_t)c * (CIN * COUT);

    // staging decomposition
    int sa_m = t >> 3;       // 0..31 (row group for A)
    int sa_c = t & 7;        // 0..7  (float4 slot -> k offset sa_c*4)
    int sb_n = t >> 1;       // 0..127
    int sb_h = t & 1;        // 0..1  (16-short half)

    for (int kt = 0; kt < 16; ++kt) {
        int k0 = kt * 32;
        __syncthreads();
        // stage A: 128 x 32 f32 -> bf16
#pragma unroll
        for (int r = 0; r < 4; ++r) {
            int m = r * 32 + sa_m;
            float4 v = *reinterpret_cast<const float4*>(xbase + (size_t)m * INFEAT + k0 + sa_c * 4);
            ushort4 sv;
            sv.x = f2bf_rne(v.x);
            sv.y = f2bf_rne(v.y);
            sv.z = f2bf_rne(v.z);
            sv.w = f2bf_rne(v.w);
            *reinterpret_cast<ushort4*>(&As[m * LDA + sa_c * 4]) = sv;
        }
        // stage B: 128 n x 32 k bf16 (n-major WT), rows bn+sb_n
        {
            const unsigned short* src = wtbase + (size_t)(bn + sb_n) * CIN + k0 + sb_h * 16;
            uint4 v0 = *reinterpret_cast<const uint4*>(src);
            uint4 v1 = *reinterpret_cast<const uint4*>(src + 8);
            *reinterpret_cast<uint4*>(&Bs[sb_n * LDA + sb_h * 16]) = v0;
            *reinterpret_cast<uint4*>(&Bs[sb_n * LDA + sb_h * 16 + 8]) = v1;
        }
        __syncthreads();
        // fragments + MFMA
        bf16x8 af[4], bfr[4];
#pragma unroll
        for (int mi = 0; mi < 4; ++mi)
            af[mi] = *reinterpret_cast<const bf16x8*>(&As[(wm * 64 + mi * 16 + lrow) * LDA + lgrp * 8]);
#pragma unroll
        for (int ni = 0; ni < 4; ++ni)
            bfr[ni] = *reinterpret_cast<const bf16x8*>(&Bs[(wn * 64 + ni * 16 + lrow) * LDA + lgrp * 8]);
#pragma unroll
        for (int mi = 0; mi < 4; ++mi)
#pragma unroll
            for (int ni = 0; ni < 4; ++ni)
                acc[mi][ni] = __builtin_amdgcn_mfma_f32_16x16x32_bf16(af[mi], bfr[ni], acc[mi][ni], 0, 0, 0);
    }

    // epilogue: add bias, write f32 C. D layout: row=(lane>>4)*4+reg, col=lane&15
    float bias[4];
#pragma unroll
    for (int ni = 0; ni < 4; ++ni)
        bias[ni] = bvec[idx * COUT + bn + wn * 64 + ni * 16 + lrow];
#pragma unroll
    for (int mi = 0; mi < 4; ++mi) {
#pragma unroll
        for (int r = 0; r < 4; ++r) {
            int row = brow + wm * 64 + mi * 16 + lgrp * 4 + r;
            float* orow = out + (size_t)row * 1024 + c * 512 + bn + wn * 64;
#pragma unroll
            for (int ni = 0; ni < 4; ++ni)
                orow[ni * 16 + lrow] = acc[mi][ni][r] + bias[ni];
        }
    }
}

extern "C" void kernel_launch(void* const* d_in, const int* in_sizes, int n_in,
                              void* d_out, int out_size, void* d_ws, size_t ws_size,
                              hipStream_t stream) {
    const float* x = (const float*)d_in[0];
    const float* W = (const float*)d_in[1];
    const float* b = (const float*)d_in[2];
    float* out = (float*)d_out;   // f32 output buffer (reference outputs are f32)

    // ws layout: [0, 64KB) partials; [64KB, +256B) topk ints; then WT bf16 (1 MB)
    float* part = (float*)d_ws;
    int* ws_idx = (int*)((char*)d_ws + 65536);
    unsigned short* WT = (unsigned short*)((char*)d_ws + 65536 + 256);

    act_partial_kernel<<<ACT_GRID, 256, 0, stream>>>(x, part);
    finalize_topk_kernel<<<1, 256, 0, stream>>>(part, out + OUT_MAIN, out + OUT_MAIN + 8, ws_idx);
    wtrans_kernel<<<dim3(16, 16, 2), dim3(32, 8), 0, stream>>>(W, ws_idx, WT);
    gemm_topk_kernel<<<dim3(BATCH / 128, COUT / 128, 2), 256, 0, stream>>>(x, WT, b, ws_idx, out);
}